// Round 3
// baseline (1797.243 us; speedup 1.0000x reference)
//
#include <hip/hip_runtime.h>
#include <hip/hip_bf16.h>
#include <math.h>

#define BB 16
#define LL 4095
#define DD 768
#define TT 768
#define SS 64
#define KK 8
#define HH 384
#define G3 1152   // 3*H
#define NSLICE 6  // WGs per (b,dir) chain
#define ISL 64    // i-values per WG slice

// ---------- 1. span means ----------
__global__ void span_mean_kernel(const float* __restrict__ hidden,
                                 const int* __restrict__ sstart,
                                 const int* __restrict__ slen,
                                 float* __restrict__ span) {
    int bs = blockIdx.x;            // b*64+s
    int b = bs >> 6;
    int st = sstart[bs];
    int ln = slen[bs];
    const float* base = hidden + ((size_t)b * LL + st) * DD;
    float inv = 1.0f / (float)ln;
    for (int d = threadIdx.x; d < DD; d += 256) {
        float acc = 0.0f;
        for (int r = 0; r < ln; ++r) acc += base[(size_t)r * DD + d];
        span[(size_t)bs * DD + d] = acc * inv;
    }
}

// ---------- 2. ctx accumulation (atomic partial sums) ----------
__global__ void ctx_accum_kernel(const float* __restrict__ hidden,
                                 const int* __restrict__ attn_len,
                                 float* __restrict__ ctx) {
    int b = blockIdx.x, chunk = blockIdx.y;
    int lim = attn_len[b] - 1;
    int l0 = chunk * 128;
    int l1 = min(l0 + 128, lim);
    if (l0 >= l1) return;
    int t = threadIdx.x;
    const float* base = hidden + (size_t)b * LL * DD;
    float a0 = 0.f, a1 = 0.f, a2 = 0.f;
    for (int l = l0; l < l1; ++l) {
        const float* row = base + (size_t)l * DD;
        a0 += row[t]; a1 += row[t + 256]; a2 += row[t + 512];
    }
    atomicAdd(&ctx[b * DD + t], a0);
    atomicAdd(&ctx[b * DD + t + 256], a1);
    atomicAdd(&ctx[b * DD + t + 512], a2);
}

// ---------- 3. rep_context = (ctx/n) @ W_ctx^T + b_ctx ----------
__global__ void repctx_kernel(const float* __restrict__ ctxsum,
                              const int* __restrict__ attn_len,
                              const float* __restrict__ W_ctx,
                              const float* __restrict__ b_ctx,
                              float* __restrict__ out_rc) {
    int b = blockIdx.x;
    int j = blockIdx.y * 256 + threadIdx.x;
    __shared__ float cv[DD];
    float inv = 1.0f / (float)(attn_len[b] - 1);
    for (int d = threadIdx.x; d < DD; d += 256) cv[d] = ctxsum[b * DD + d] * inv;
    __syncthreads();
    const float* wr = W_ctx + (size_t)j * DD;
    float acc = b_ctx[j];
    for (int d = 0; d < DD; ++d) acc += wr[d] * cv[d];
    out_rc[b * TT + j] = acc;
}

// ---------- 4. transpose W_hh (fp32), layout [dir][k4][gate][i] as float4 ----------
__global__ void whh_pack_kernel(const float* __restrict__ Wf,
                                const float* __restrict__ Wb,
                                float* __restrict__ wtb) {
    int o = blockIdx.x * 256 + threadIdx.x;   // [0, 2*96*3*384)
    if (o >= 2 * 96 * 3 * 384) return;
    int i = o % 384;
    int r = o / 384;
    int g = r % 3; r /= 3;
    int k4 = r % 96;
    int dir = r / 96;
    const float* W = dir ? Wb : Wf;
    int j = g * HH + i;
    const float* wrow = W + (size_t)j * HH + k4 * 4;
    float4 v;
    v.x = wrow[0]; v.y = wrow[1]; v.z = wrow[2]; v.w = wrow[3];
    ((float4*)wtb)[o] = v;
}

// ---------- 5. gi = span @ W_ih^T + b_ih (+ b_hh for r,z gates) ----------
__global__ __launch_bounds__(256) void gi_gemm_kernel(
        const float* __restrict__ span,
        const float* __restrict__ Wf, const float* __restrict__ Wb,
        const float* __restrict__ bihf, const float* __restrict__ bhhf,
        const float* __restrict__ bihb, const float* __restrict__ bhhb,
        float* __restrict__ gi) {
    int dir = blockIdx.z;
    const float* W = dir ? Wb : Wf;
    const float* bih = dir ? bihb : bihf;
    const float* bhh = dir ? bhhb : bhhf;
    int m0 = blockIdx.x * 64, n0 = blockIdx.y * 64;
    __shared__ float As[64][17];
    __shared__ float Bs[64][17];
    int t = threadIdx.x, tx = t & 15, ty = t >> 4;
    float acc[4][4] = {{0.f}};
    for (int k0 = 0; k0 < DD; k0 += 16) {
        for (int e = t; e < 1024; e += 256) {
            int r = e >> 4, c = e & 15;
            As[r][c] = span[(size_t)(m0 + r) * DD + k0 + c];
            Bs[r][c] = W[(size_t)(n0 + r) * DD + k0 + c];
        }
        __syncthreads();
#pragma unroll
        for (int kk = 0; kk < 16; ++kk) {
            float a[4], bv[4];
#pragma unroll
            for (int i = 0; i < 4; ++i) a[i] = As[ty * 4 + i][kk];
#pragma unroll
            for (int j = 0; j < 4; ++j) bv[j] = Bs[tx * 4 + j][kk];
#pragma unroll
            for (int i = 0; i < 4; ++i)
#pragma unroll
                for (int j = 0; j < 4; ++j) acc[i][j] += a[i] * bv[j];
        }
        __syncthreads();
    }
#pragma unroll
    for (int i = 0; i < 4; ++i)
#pragma unroll
        for (int j = 0; j < 4; ++j) {
            int m = m0 + ty * 4 + i, n = n0 + tx * 4 + j;
            float v = acc[i][j] + bih[n] + (n < 2 * HH ? bhh[n] : 0.0f);
            gi[((size_t)dir * 1024 + m) * G3 + n] = v;
        }
}

// ---------- 6. GRU scan: 6 WGs per chain, flag-synced, W slice from L2 ----------
// Numerics: per-row FMA sequence identical to the R2 passing scan.
__global__ __launch_bounds__(192) void scan_sync_kernel(
        const float* __restrict__ gi,
        const float* __restrict__ wtb,
        const float* __restrict__ bhhf, const float* __restrict__ bhhb,
        float* __restrict__ hbuf,     // [2][32][384]
        int* __restrict__ flags,      // [32][64]
        float* __restrict__ repac) {
    int wg = blockIdx.x;              // 0..191
    int chain = wg / NSLICE;          // 0..31
    int slice = wg % NSLICE;          // 0..5
    int b = chain & 15, dir = chain >> 4;
    int t = threadIdx.x;              // 0..191
    int g = t >> 6;                   // gate 0..2
    int ii = t & 63;
    int i = slice * ISL + ii;         // this thread's hidden index

    __shared__ __align__(16) float hs[HH];
    __shared__ float ga[3][ISL];

    const float4* wp = ((const float4*)wtb) + (size_t)dir * 96 * 3 * 384;
    const float* gib = gi + ((size_t)dir * 1024 + b * 64) * G3;
    float bhn = (dir ? bhhb : bhhf)[2 * HH + i];
    int* flagc = flags + chain * 64;

    for (int s = 0; s < 64; ++s) {
        int p = dir ? (63 - s) : s;
        // load h_s (agent-scope: produced by sibling WGs on other XCDs)
        const float* hsrc = hbuf + (((s & 1) * 32 + chain) * HH);
        hs[t] = __hip_atomic_load(hsrc + t, __ATOMIC_RELAXED, __HIP_MEMORY_SCOPE_AGENT);
        hs[t + 192] = __hip_atomic_load(hsrc + t + 192, __ATOMIC_RELAXED, __HIP_MEMORY_SCOPE_AGENT);
        __syncthreads();
        // prefetch gi row values (only used by epilogue threads)
        float gr = 0.f, gz = 0.f, gn = 0.f;
        if (t < ISL) {
            const float* grow = gib + (size_t)p * G3;
            int iq = slice * ISL + t;
            gr = grow[iq]; gz = grow[HH + iq]; gn = grow[2 * HH + iq];
        }
        // one W row dot per thread; W coalesced from L2, h broadcast from LDS
        float acc = 0.f;
        const float4* h4 = (const float4*)hs;
#pragma unroll 8
        for (int k4 = 0; k4 < 96; ++k4) {
            float4 w = wp[(k4 * 3 + g) * 384 + i];
            float4 hv = h4[k4];
            acc += w.x * hv.x + w.y * hv.y + w.z * hv.z + w.w * hv.w;
        }
        ga[g][ii] = acc;
        __syncthreads();
        // epilogue: threads 0..63 finalize h_new for their i
        if (t < ISL) {
            int iq = slice * ISL + t;
            float r = 1.0f / (1.0f + expf(-(gr + ga[0][t])));
            float z = 1.0f / (1.0f + expf(-(gz + ga[1][t])));
            float n = tanhf(gn + r * (ga[2][t] + bhn));
            float hnew = (1.0f - z) * n + z * hs[iq];
            hbuf[(((s + 1) & 1) * 32 + chain) * HH + iq] = hnew;
            repac[(size_t)(b * 64 + p) * TT + dir * HH + iq] = hnew;
        }
        if (s < 63) {
            __threadfence();          // make h_new agent-visible before flag
            __syncthreads();
            if (t == 0) {
                __hip_atomic_fetch_add(flagc + s, 1, __ATOMIC_RELEASE, __HIP_MEMORY_SCOPE_AGENT);
                while (__hip_atomic_load(flagc + s, __ATOMIC_ACQUIRE, __HIP_MEMORY_SCOPE_AGENT) < NSLICE) {
                    __builtin_amdgcn_s_sleep(2);
                }
            }
            __syncthreads();
        }
    }
}

// ---------- 7. q and k dot products (one wave each, fp64 accumulation) ----------
__global__ void qkv_kernel(const float* __restrict__ repac,
                           const float* __restrict__ repctx,
                           const float* __restrict__ Wfind,
                           float* __restrict__ qv, float* __restrict__ kv) {
    int w = blockIdx.x * 4 + (threadIdx.x >> 6);
    int lane = threadIdx.x & 63;
    const float* row;
    const float* vec;
    float* dst;
    if (w < 1024) {
        row = repac + (size_t)w * TT;
        vec = Wfind;
        dst = qv + w;
    } else {
        int u = w - 1024;
        int b = u / 65, j = u % 65;
        row = (j < 64) ? (repac + (size_t)(b * 64 + j) * TT) : (repctx + (size_t)b * TT);
        vec = Wfind + TT;
        dst = kv + u;
    }
    double acc = 0.0;
    for (int d = lane; d < TT; d += 64) acc += (double)row[d] * (double)vec[d];
#pragma unroll
    for (int off = 32; off > 0; off >>= 1) acc += __shfl_down(acc, off);
    if (lane == 0) *dst = (float)acc;
}

// ---------- 8. top-k on fp32-quantized scores (np-mirrored), tie -> lower idx ----------
__global__ void topk_kernel(const float* __restrict__ qv,
                            const float* __restrict__ kv,
                            float* __restrict__ vals_out,
                            float* __restrict__ idx_out,
                            int* __restrict__ idxw) {
    int t = threadIdx.x;
    int bs = blockIdx.x * 256 + t;
    int b = bs >> 6;
    int b0 = (blockIdx.x * 256) >> 6;       // 4 batches per block
    __shared__ float kvs[4 * 65];
    for (int e = t; e < 4 * 65; e += 256) kvs[e] = kv[(b0 + e / 65) * 65 + e % 65];
    __syncthreads();
    const float* myk = kvs + (b - b0) * 65;
    float q = qv[bs];
    float sc[65];
#pragma unroll 1
    for (int j = 0; j < 65; ++j) {
        float x = q + myk[j];                 // fp32 add, as np broadcast-add
        float e = (float)exp(-(double)x);     // ~correctly-rounded f32 exp
        sc[j] = 1.0f / (1.0f + e);            // fp32 add + fp32 divide, as np
    }
    unsigned long long taken = 0ull;
    bool tk64 = false;
    for (int kk = 0; kk < 8; ++kk) {
        float best = -3.0e38f;
        int bj = 0;
        for (int j = 0; j < 65; ++j) {
            bool tkn = (j < 64) ? (((taken >> j) & 1ull) != 0ull) : tk64;
            float v = sc[j];
            if (!tkn && v > best) { best = v; bj = j; }   // strict > => lowest index wins ties
        }
        if (bj < 64) taken |= (1ull << bj); else tk64 = true;
        vals_out[bs * 8 + kk] = best;
        idx_out[bs * 8 + kk] = (float)bj;
        idxw[bs * 8 + kk] = bj;
    }
}

// ---------- 9. v1 gather ----------
__global__ void v1_kernel(const float* __restrict__ repac,
                          const float* __restrict__ repctx,
                          const int* __restrict__ idxw,
                          float* __restrict__ v1) {
    int bs = blockIdx.x;
    int b = bs >> 6;
    int t = threadIdx.x;
    for (int kk = 0; kk < 8; ++kk) {
        int j = idxw[bs * 8 + kk];
        const float* src = (j < 64) ? (repac + (size_t)(b * 64 + j) * TT)
                                    : (repctx + (size_t)b * TT);
        float* dst = v1 + ((size_t)bs * 8 + kk) * TT;
        for (int d = t; d < DD; d += 256) dst[d] = src[d];
    }
}

extern "C" void kernel_launch(void* const* d_in, const int* in_sizes, int n_in,
                              void* d_out, int out_size, void* d_ws, size_t ws_size,
                              hipStream_t stream) {
    const float* hidden    = (const float*)d_in[0];
    const float* W_ih_f    = (const float*)d_in[1];
    const float* W_hh_f    = (const float*)d_in[2];
    const float* b_ih_f    = (const float*)d_in[3];
    const float* b_hh_f    = (const float*)d_in[4];
    const float* W_ih_b    = (const float*)d_in[5];
    const float* W_hh_b    = (const float*)d_in[6];
    const float* b_ih_b    = (const float*)d_in[7];
    const float* b_hh_b    = (const float*)d_in[8];
    const float* W_ctx     = (const float*)d_in[9];
    const float* b_ctx     = (const float*)d_in[10];
    const float* W_find    = (const float*)d_in[11];
    const int*   attn_len  = (const int*)d_in[12];
    const int*   span_start= (const int*)d_in[13];
    const int*   span_len  = (const int*)d_in[14];
    (void)in_sizes; (void)n_in; (void)out_size; (void)ws_size;

    // workspace layout (floats)
    float* ws   = (float*)d_ws;
    float* span = ws;                       // 1024*768          = 786432
    float* gi   = span + 786432;            // 2*1024*1152       = 2359296
    float* ctx  = gi + 2359296;             // 16*768            = 12288
    float* qv   = ctx + 12288;              // 1024
    float* kv   = qv + 1024;                // 16*65 = 1040
    int*   idxw = (int*)(kv + 1040);        // 8192
    float* wtb  = (float*)(idxw + 8192);    // 884736 floats (float4-packed W^T)
    float* hbuf = wtb + 884736;             // 2*32*384 = 24576
    int*   flags= (int*)(hbuf + 24576);     // 32*64 = 2048

    // output layout (floats)
    float* out      = (float*)d_out;
    float* o_repac  = out;                  // 786432
    float* o_repctx = out + 786432;         // 12288
    float* o_v1     = out + 798720;         // 6291456
    float* o_vals   = out + 7090176;        // 8192
    float* o_idx    = out + 7098368;        // 8192

    hipMemsetAsync(ctx, 0, (size_t)BB * DD * sizeof(float), stream);
    hipMemsetAsync(hbuf, 0, (size_t)32 * HH * sizeof(float), stream);   // h_0 = 0 (parity 0)
    hipMemsetAsync(flags, 0, (size_t)32 * 64 * sizeof(int), stream);

    span_mean_kernel<<<1024, 256, 0, stream>>>(hidden, span_start, span_len, span);
    ctx_accum_kernel<<<dim3(BB, 32), 256, 0, stream>>>(hidden, attn_len, ctx);
    repctx_kernel<<<dim3(BB, 3), 256, 0, stream>>>(ctx, attn_len, W_ctx, b_ctx, o_repctx);
    whh_pack_kernel<<<864, 256, 0, stream>>>(W_hh_f, W_hh_b, wtb);
    gi_gemm_kernel<<<dim3(16, 18, 2), 256, 0, stream>>>(span, W_ih_f, W_ih_b,
                                                        b_ih_f, b_hh_f, b_ih_b, b_hh_b, gi);
    scan_sync_kernel<<<192, 192, 0, stream>>>(gi, wtb, b_hh_f, b_hh_b, hbuf, flags, o_repac);
    qkv_kernel<<<516, 256, 0, stream>>>(o_repac, o_repctx, W_find, qv, kv);
    topk_kernel<<<4, 256, 0, stream>>>(qv, kv, o_vals, o_idx, idxw);
    v1_kernel<<<1024, 256, 0, stream>>>(o_repac, o_repctx, idxw, o_v1);
}

// Round 4
// 1186.480 us; speedup vs baseline: 1.5148x; 1.5148x over previous
//
#include <hip/hip_runtime.h>
#include <hip/hip_bf16.h>
#include <math.h>

#define BB 16
#define LL 4095
#define DD 768
#define TT 768
#define SS 64
#define KK 8
#define HH 384
#define G3 1152   // 3*H
#define NWPD 24   // WGs per direction for the coop scan

// ---------- 1. span means ----------
__global__ void span_mean_kernel(const float* __restrict__ hidden,
                                 const int* __restrict__ sstart,
                                 const int* __restrict__ slen,
                                 float* __restrict__ span) {
    int bs = blockIdx.x;            // b*64+s
    int b = bs >> 6;
    int st = sstart[bs];
    int ln = slen[bs];
    const float* base = hidden + ((size_t)b * LL + st) * DD;
    float inv = 1.0f / (float)ln;
    for (int d = threadIdx.x; d < DD; d += 256) {
        float acc = 0.0f;
        for (int r = 0; r < ln; ++r) acc += base[(size_t)r * DD + d];
        span[(size_t)bs * DD + d] = acc * inv;
    }
}

// ---------- 2. ctx accumulation (atomic partial sums) ----------
__global__ void ctx_accum_kernel(const float* __restrict__ hidden,
                                 const int* __restrict__ attn_len,
                                 float* __restrict__ ctx) {
    int b = blockIdx.x, chunk = blockIdx.y;
    int lim = attn_len[b] - 1;
    int l0 = chunk * 128;
    int l1 = min(l0 + 128, lim);
    if (l0 >= l1) return;
    int t = threadIdx.x;
    const float* base = hidden + (size_t)b * LL * DD;
    float a0 = 0.f, a1 = 0.f, a2 = 0.f;
    for (int l = l0; l < l1; ++l) {
        const float* row = base + (size_t)l * DD;
        a0 += row[t]; a1 += row[t + 256]; a2 += row[t + 512];
    }
    atomicAdd(&ctx[b * DD + t], a0);
    atomicAdd(&ctx[b * DD + t + 256], a1);
    atomicAdd(&ctx[b * DD + t + 512], a2);
}

// ---------- 3. rep_context = (ctx/n) @ W_ctx^T + b_ctx ----------
__global__ void repctx_kernel(const float* __restrict__ ctxsum,
                              const int* __restrict__ attn_len,
                              const float* __restrict__ W_ctx,
                              const float* __restrict__ b_ctx,
                              float* __restrict__ out_rc) {
    int b = blockIdx.x;
    int j = blockIdx.y * 256 + threadIdx.x;
    __shared__ float cv[DD];
    float inv = 1.0f / (float)(attn_len[b] - 1);
    for (int d = threadIdx.x; d < DD; d += 256) cv[d] = ctxsum[b * DD + d] * inv;
    __syncthreads();
    const float* wr = W_ctx + (size_t)j * DD;
    float acc = b_ctx[j];
    for (int d = 0; d < DD; ++d) acc += wr[d] * cv[d];
    out_rc[b * TT + j] = acc;
}

// ---------- 4. gi = span @ W_ih^T + b_ih (+ b_hh for r,z gates) ----------
__global__ __launch_bounds__(256) void gi_gemm_kernel(
        const float* __restrict__ span,
        const float* __restrict__ Wf, const float* __restrict__ Wb,
        const float* __restrict__ bihf, const float* __restrict__ bhhf,
        const float* __restrict__ bihb, const float* __restrict__ bhhb,
        float* __restrict__ gi) {
    int dir = blockIdx.z;
    const float* W = dir ? Wb : Wf;
    const float* bih = dir ? bihb : bihf;
    const float* bhh = dir ? bhhb : bhhf;
    int m0 = blockIdx.x * 64, n0 = blockIdx.y * 64;
    __shared__ float As[64][17];
    __shared__ float Bs[64][17];
    int t = threadIdx.x, tx = t & 15, ty = t >> 4;
    float acc[4][4] = {{0.f}};
    for (int k0 = 0; k0 < DD; k0 += 16) {
        for (int e = t; e < 1024; e += 256) {
            int r = e >> 4, c = e & 15;
            As[r][c] = span[(size_t)(m0 + r) * DD + k0 + c];
            Bs[r][c] = W[(size_t)(n0 + r) * DD + k0 + c];
        }
        __syncthreads();
#pragma unroll
        for (int kk = 0; kk < 16; ++kk) {
            float a[4], bv[4];
#pragma unroll
            for (int i = 0; i < 4; ++i) a[i] = As[ty * 4 + i][kk];
#pragma unroll
            for (int j = 0; j < 4; ++j) bv[j] = Bs[tx * 4 + j][kk];
#pragma unroll
            for (int i = 0; i < 4; ++i)
#pragma unroll
                for (int j = 0; j < 4; ++j) acc[i][j] += a[i] * bv[j];
        }
        __syncthreads();
    }
#pragma unroll
    for (int i = 0; i < 4; ++i)
#pragma unroll
        for (int j = 0; j < 4; ++j) {
            int m = m0 + ty * 4 + i, n = n0 + tx * 4 + j;
            float v = acc[i][j] + bih[n] + (n < 2 * HH ? bhh[n] : 0.0f);
            gi[((size_t)dir * 1024 + m) * G3 + n] = v;
        }
}

// ---------- 5. GRU coop scan: W stationary in VGPRs, 24 WGs/dir ----------
// Thread (i_loc = t>>4, kseg = t&15) holds W rows {g*384 + w*16+i_loc} at
// k in {kseg*4 + 64j + q : j<6, q<4} -> 72 regs. h staged in LDS each step.
// Cross-WG sync: relaxed agent polls (no L2 invalidate per poll), one
// acquire on success; h_new published via relaxed agent (write-through)
// stores; slot released after __syncthreads' vmcnt drain.
__global__ __launch_bounds__(256) void scan_coop_kernel(
        const float* __restrict__ gi,
        const float* __restrict__ Whf, const float* __restrict__ Whb,
        const float* __restrict__ bhhf, const float* __restrict__ bhhb,
        float* __restrict__ hbuf,   // [2 parity][2 dir][16 b][384]
        int* __restrict__ slots,    // [2 dir][24] stride 16 ints
        float* __restrict__ repac) {
    int wg = blockIdx.x;            // 0..47
    int dir = wg / NWPD;
    int w = wg % NWPD;
    int t = threadIdx.x;
    int kseg = t & 15, i_loc = t >> 4;
    int i_glob = w * 16 + i_loc;
    int b_e = t & 15;               // epilogue batch for this thread
    const float* Wh = dir ? Whb : Whf;

    // W fragments into registers (once)
    float4 wr[3][6];
#pragma unroll
    for (int g = 0; g < 3; ++g)
#pragma unroll
        for (int j = 0; j < 6; ++j)
            wr[g][j] = *(const float4*)(Wh + (size_t)(g * HH + i_glob) * HH + kseg * 4 + 64 * j);
    float bhn = (dir ? bhhb : bhhf)[2 * HH + i_glob];

    __shared__ __align__(16) float hs[6144];          // [16 b][384]
    __shared__ __align__(16) float part[16 * 16 * 20]; // [kseg][islot][4bl*4 + pad]
    float4* hs4 = (float4*)hs;
    float4* part4 = (float4*)part;
    int* myslot = slots + (dir * NWPD + w) * 16;
    int* dirslots = slots + dir * NWPD * 16;

    for (int s = 0; s < 64; ++s) {
        int p = dir ? (63 - s) : s;
        // ---- wait for all WGs of this dir to finish step s-1 ----
        if (s > 0) {
            if (t < 64) {
                for (;;) {
                    int v = 0x7fffffff;
                    if (t < NWPD)
                        v = __hip_atomic_load(dirslots + t * 16, __ATOMIC_RELAXED, __HIP_MEMORY_SCOPE_AGENT);
                    if (__all(v >= s)) break;
                    __builtin_amdgcn_s_sleep(1);
                }
            }
            if (t == 0)
                (void)__hip_atomic_load(myslot, __ATOMIC_ACQUIRE, __HIP_MEMORY_SCOPE_AGENT);
            __syncthreads();
        }
        // ---- gi prefetch for this thread's epilogue (i_loc, b_e) ----
        const float* grow = gi + ((size_t)dir * 1024 + b_e * 64 + p) * G3;
        float g_r = grow[i_glob], g_z = grow[HH + i_glob], g_n = grow[2 * HH + i_glob];
        // ---- stage h into LDS ----
        const float4* hsrc = (const float4*)(hbuf + (size_t)((s & 1) * 2 + dir) * 6144);
#pragma unroll
        for (int j = 0; j < 6; ++j) hs4[t + 256 * j] = hsrc[t + 256 * j];
        __syncthreads();
        // ---- 4 batch-quarters: partials + epilogue ----
#pragma unroll 1
        for (int q = 0; q < 4; ++q) {
#pragma unroll
            for (int bl = 0; bl < 4; ++bl) {
                int b = q * 4 + bl;
                float4 hq[6];
#pragma unroll
                for (int j = 0; j < 6; ++j) hq[j] = hs4[b * 96 + kseg + 16 * j];
                float ar = 0.f, az = 0.f, an = 0.f;
#pragma unroll
                for (int j = 0; j < 6; ++j) {
                    ar += wr[0][j].x * hq[j].x + wr[0][j].y * hq[j].y + wr[0][j].z * hq[j].z + wr[0][j].w * hq[j].w;
                    az += wr[1][j].x * hq[j].x + wr[1][j].y * hq[j].y + wr[1][j].z * hq[j].z + wr[1][j].w * hq[j].w;
                    an += wr[2][j].x * hq[j].x + wr[2][j].y * hq[j].y + wr[2][j].z * hq[j].z + wr[2][j].w * hq[j].w;
                }
                part4[kseg * 80 + i_loc * 5 + bl] = make_float4(ar, az, an, 0.f);
            }
            __syncthreads();
            if ((b_e >> 2) == q) {
                int bl = b_e & 3;
                float sr = 0.f, sz = 0.f, sn = 0.f;
#pragma unroll
                for (int ks = 0; ks < 16; ++ks) {
                    int base = ks * 320 + i_loc * 20 + bl * 4;
                    sr += part[base]; sz += part[base + 1]; sn += part[base + 2];
                }
                float r = 1.0f / (1.0f + expf(-(g_r + sr)));
                float z = 1.0f / (1.0f + expf(-(g_z + sz)));
                float n = tanhf(g_n + r * (sn + bhn));
                float hold = hs[b_e * 384 + i_glob];
                float hnew = (1.0f - z) * n + z * hold;
                __hip_atomic_store(hbuf + (size_t)(((s + 1) & 1) * 2 + dir) * 6144 + b_e * 384 + i_glob,
                                   hnew, __ATOMIC_RELAXED, __HIP_MEMORY_SCOPE_AGENT);
                repac[(size_t)(b_e * 64 + p) * TT + dir * HH + i_glob] = hnew;
            }
            __syncthreads();
        }
        // ---- publish completion of step s ----
        if (s < 63) {
            if (t == 0)
                __hip_atomic_store(myslot, s + 1, __ATOMIC_RELEASE, __HIP_MEMORY_SCOPE_AGENT);
        }
    }
}

// ---------- 6. q and k dot products (one wave each, fp64 accumulation) ----------
__global__ void qkv_kernel(const float* __restrict__ repac,
                           const float* __restrict__ repctx,
                           const float* __restrict__ Wfind,
                           float* __restrict__ qv, float* __restrict__ kv) {
    int w = blockIdx.x * 4 + (threadIdx.x >> 6);
    int lane = threadIdx.x & 63;
    const float* row;
    const float* vec;
    float* dst;
    if (w < 1024) {
        row = repac + (size_t)w * TT;
        vec = Wfind;
        dst = qv + w;
    } else {
        int u = w - 1024;
        int b = u / 65, j = u % 65;
        row = (j < 64) ? (repac + (size_t)(b * 64 + j) * TT) : (repctx + (size_t)b * TT);
        vec = Wfind + TT;
        dst = kv + u;
    }
    double acc = 0.0;
    for (int d = lane; d < TT; d += 64) acc += (double)row[d] * (double)vec[d];
#pragma unroll
    for (int off = 32; off > 0; off >>= 1) acc += __shfl_down(acc, off);
    if (lane == 0) *dst = (float)acc;
}

// ---------- 7. top-k on fp32-quantized scores (np-mirrored), tie -> lower idx ----------
__global__ void topk_kernel(const float* __restrict__ qv,
                            const float* __restrict__ kv,
                            float* __restrict__ vals_out,
                            float* __restrict__ idx_out,
                            int* __restrict__ idxw) {
    int t = threadIdx.x;
    int bs = blockIdx.x * 256 + t;
    int b = bs >> 6;
    int b0 = (blockIdx.x * 256) >> 6;       // 4 batches per block
    __shared__ float kvs[4 * 65];
    for (int e = t; e < 4 * 65; e += 256) kvs[e] = kv[(b0 + e / 65) * 65 + e % 65];
    __syncthreads();
    const float* myk = kvs + (b - b0) * 65;
    float q = qv[bs];
    float sc[65];
#pragma unroll 1
    for (int j = 0; j < 65; ++j) {
        float x = q + myk[j];                 // fp32 add, as np broadcast-add
        float e = (float)exp(-(double)x);     // ~correctly-rounded f32 exp
        sc[j] = 1.0f / (1.0f + e);            // fp32 add + fp32 divide, as np
    }
    unsigned long long taken = 0ull;
    bool tk64 = false;
    for (int kk = 0; kk < 8; ++kk) {
        float best = -3.0e38f;
        int bj = 0;
        for (int j = 0; j < 65; ++j) {
            bool tkn = (j < 64) ? (((taken >> j) & 1ull) != 0ull) : tk64;
            float v = sc[j];
            if (!tkn && v > best) { best = v; bj = j; }   // strict > => lowest index wins ties
        }
        if (bj < 64) taken |= (1ull << bj); else tk64 = true;
        vals_out[bs * 8 + kk] = best;
        idx_out[bs * 8 + kk] = (float)bj;
        idxw[bs * 8 + kk] = bj;
    }
}

// ---------- 8. v1 gather ----------
__global__ void v1_kernel(const float* __restrict__ repac,
                          const float* __restrict__ repctx,
                          const int* __restrict__ idxw,
                          float* __restrict__ v1) {
    int bs = blockIdx.x;
    int b = bs >> 6;
    int t = threadIdx.x;
    for (int kk = 0; kk < 8; ++kk) {
        int j = idxw[bs * 8 + kk];
        const float* src = (j < 64) ? (repac + (size_t)(b * 64 + j) * TT)
                                    : (repctx + (size_t)b * TT);
        float* dst = v1 + ((size_t)bs * 8 + kk) * TT;
        for (int d = t; d < DD; d += 256) dst[d] = src[d];
    }
}

extern "C" void kernel_launch(void* const* d_in, const int* in_sizes, int n_in,
                              void* d_out, int out_size, void* d_ws, size_t ws_size,
                              hipStream_t stream) {
    const float* hidden    = (const float*)d_in[0];
    const float* W_ih_f    = (const float*)d_in[1];
    const float* W_hh_f    = (const float*)d_in[2];
    const float* b_ih_f    = (const float*)d_in[3];
    const float* b_hh_f    = (const float*)d_in[4];
    const float* W_ih_b    = (const float*)d_in[5];
    const float* W_hh_b    = (const float*)d_in[6];
    const float* b_ih_b    = (const float*)d_in[7];
    const float* b_hh_b    = (const float*)d_in[8];
    const float* W_ctx     = (const float*)d_in[9];
    const float* b_ctx     = (const float*)d_in[10];
    const float* W_find    = (const float*)d_in[11];
    const int*   attn_len  = (const int*)d_in[12];
    const int*   span_start= (const int*)d_in[13];
    const int*   span_len  = (const int*)d_in[14];
    (void)in_sizes; (void)n_in; (void)out_size; (void)ws_size;

    // workspace layout (floats)
    float* ws   = (float*)d_ws;
    float* span = ws;                       // 786432
    float* gi   = span + 786432;            // 2359296
    float* ctx  = gi + 2359296;             // 12288
    float* qv   = ctx + 12288;              // 1024
    float* kv   = qv + 1024;                // 1040
    int*   idxw = (int*)(kv + 1040);        // 8192
    float* hbuf = (float*)(idxw + 8192);    // 2*2*16*384 = 24576
    int*   slots= (int*)(hbuf + 24576);     // 2*24*16 = 768

    // output layout (floats)
    float* out      = (float*)d_out;
    float* o_repac  = out;                  // 786432
    float* o_repctx = out + 786432;         // 12288
    float* o_v1     = out + 798720;         // 6291456
    float* o_vals   = out + 7090176;        // 8192
    float* o_idx    = out + 7098368;        // 8192

    hipMemsetAsync(ctx, 0, (size_t)BB * DD * sizeof(float), stream);
    hipMemsetAsync(hbuf, 0, (size_t)24576 * sizeof(float), stream);   // h_0 = 0 (both parities)
    hipMemsetAsync(slots, 0, (size_t)768 * sizeof(int), stream);

    span_mean_kernel<<<1024, 256, 0, stream>>>(hidden, span_start, span_len, span);
    ctx_accum_kernel<<<dim3(BB, 32), 256, 0, stream>>>(hidden, attn_len, ctx);
    repctx_kernel<<<dim3(BB, 3), 256, 0, stream>>>(ctx, attn_len, W_ctx, b_ctx, o_repctx);
    gi_gemm_kernel<<<dim3(16, 18, 2), 256, 0, stream>>>(span, W_ih_f, W_ih_b,
                                                        b_ih_f, b_hh_f, b_ih_b, b_hh_b, gi);
    scan_coop_kernel<<<48, 256, 0, stream>>>(gi, W_hh_f, W_hh_b, b_hh_f, b_hh_b,
                                             hbuf, slots, o_repac);
    qkv_kernel<<<516, 256, 0, stream>>>(o_repac, o_repctx, W_find, qv, kv);
    topk_kernel<<<4, 256, 0, stream>>>(qv, kv, o_vals, o_idx, idxw);
    v1_kernel<<<1024, 256, 0, stream>>>(o_repac, o_repctx, idxw, o_v1);
}